// Round 1
// baseline (162.778 us; speedup 1.0000x reference)
//
#include <hip/hip_runtime.h>
#include <cstdint>
#include <cstddef>

#define LEVELS 16
#define TABLE_SIZE 524288   // 2^19
#define CROP 256            // memorized_crop_size (fixed by setup_inputs)

// grid resolutions: int(round(16 * 1.5^l)), Python banker's rounding (121.5 -> 122)
__device__ __constant__ int c_levelN[LEVELS] = {
    16, 24, 36, 54, 81, 122, 182, 273, 410, 615, 923, 1384, 2076, 3114, 4671, 7006
};

__global__ __launch_bounds__(256)
void HashTableEncoder2D_59339268161685_kernel(const float* __restrict__ tables,
                                              const int* __restrict__ x0,
                                              const int* __restrict__ y0,
                                              float* __restrict__ out)
{
    const int tid = blockIdx.x * 256 + threadIdx.x;
    const int j = tid & (CROP - 1);          // x within crop (fastest)
    const int i = (tid >> 8) & (CROP - 1);   // y within crop
    const int b = tid >> 16;                 // batch

    // pixel-center global coordinates; exact in f32 (all values k+0.5, k<4096)
    const float px = (float)x0[b] + ((float)j + 0.5f);
    const float py = (float)y0[b] + ((float)i + 0.5f);

    float* outp = out + (size_t)b * (size_t)(32 * CROP * CROP) + i * CROP + j;

    #pragma unroll
    for (int l = 0; l < LEVELS; ++l) {
        // per-level seed: (cA ^ (l*cB)) truncated to 32 bits — compile-time const
        const uint32_t seed =
            (uint32_t)(15485907386658061715ULL ^ ((uint64_t)l * 11400714819323198485ULL));
        // scale = N/4096: dyadic rational, exact in f32 (matches f32(N/4096.0))
        const float scale = (float)c_levelN[l] * (1.0f / 4096.0f);

        const float gx = px * scale;
        const float gy = py * scale;
        const float fx0f = floorf(gx);
        const float fy0f = floorf(gy);
        const int ix0 = (int)fx0f;
        const int iy0 = (int)fy0f;
        const float fx = gx - fx0f;
        const float fy = gy - fy0f;

        const uint32_t hx0 = (uint32_t)ix0 * 2654435761u;
        const uint32_t hx1 = (uint32_t)(ix0 + 1) * 2654435761u;
        const uint32_t hy0 = ((uint32_t)iy0 * 805459861u) ^ seed;
        const uint32_t hy1 = ((uint32_t)(iy0 + 1) * 805459861u) ^ seed;

        const float2* __restrict__ T =
            (const float2*)(tables + (size_t)l * (size_t)(TABLE_SIZE * 2));
        const float2 f00 = T[(hx0 ^ hy0) & (TABLE_SIZE - 1)];
        const float2 f10 = T[(hx1 ^ hy0) & (TABLE_SIZE - 1)];
        const float2 f01 = T[(hx0 ^ hy1) & (TABLE_SIZE - 1)];
        const float2 f11 = T[(hx1 ^ hy1) & (TABLE_SIZE - 1)];

        const float w00 = (1.0f - fx) * (1.0f - fy);
        const float w10 = fx * (1.0f - fy);
        const float w01 = (1.0f - fx) * fy;
        const float w11 = fx * fy;

        const float e0 = w00 * f00.x + w10 * f10.x + w01 * f01.x + w11 * f11.x;
        const float e1 = w00 * f00.y + w10 * f10.y + w01 * f01.y + w11 * f11.y;

        outp[(2 * l)     * (CROP * CROP)] = e0;
        outp[(2 * l + 1) * (CROP * CROP)] = e1;
    }
}

extern "C" void kernel_launch(void* const* d_in, const int* in_sizes, int n_in,
                              void* d_out, int out_size, void* d_ws, size_t ws_size,
                              hipStream_t stream)
{
    const float* tables = (const float*)d_in[0];
    const int*   x0     = (const int*)d_in[1];
    const int*   y0     = (const int*)d_in[2];
    // d_in[3] = memorized_crop_size (256), d_in[4] = complete_tile_size (4096):
    // compile-time constants of this problem instance.
    float* out = (float*)d_out;

    const int B = in_sizes[1];                 // 16
    const int total = B * CROP * CROP;         // 1,048,576 threads
    const int blocks = total / 256;            // 4096 blocks

    HashTableEncoder2D_59339268161685_kernel<<<blocks, 256, 0, stream>>>(tables, x0, y0, out);
}

// Round 2
// 155.181 us; speedup vs baseline: 1.0490x; 1.0490x over previous
//
#include <hip/hip_runtime.h>
#include <cstdint>
#include <cstddef>

#define LEVELS 16
#define TABLE_SIZE 524288   // 2^19
#define CROP 256            // memorized_crop_size (fixed by setup_inputs)
#define PIX_PER_LEVEL (16 * CROP * CROP)        // B=16 -> 1,048,576 pixels
#define BLOCKS_PER_LEVEL (PIX_PER_LEVEL / 256)  // 4096

// grid resolutions: int(round(16 * 1.5^l)), Python banker's rounding (121.5 -> 122)
__device__ __constant__ int c_levelN[LEVELS] = {
    16, 24, 36, 54, 81, 122, 182, 273, 410, 615, 923, 1384, 2076, 3114, 4671, 7006
};
// seeds: (15485907386658061715 ^ (l * 11400714819323198485)) & 0xFFFFFFFF
__device__ __constant__ uint32_t c_seed[LEVELS] = {
    (uint32_t)(15485907386658061715ULL ^ ( 0ULL * 11400714819323198485ULL)),
    (uint32_t)(15485907386658061715ULL ^ ( 1ULL * 11400714819323198485ULL)),
    (uint32_t)(15485907386658061715ULL ^ ( 2ULL * 11400714819323198485ULL)),
    (uint32_t)(15485907386658061715ULL ^ ( 3ULL * 11400714819323198485ULL)),
    (uint32_t)(15485907386658061715ULL ^ ( 4ULL * 11400714819323198485ULL)),
    (uint32_t)(15485907386658061715ULL ^ ( 5ULL * 11400714819323198485ULL)),
    (uint32_t)(15485907386658061715ULL ^ ( 6ULL * 11400714819323198485ULL)),
    (uint32_t)(15485907386658061715ULL ^ ( 7ULL * 11400714819323198485ULL)),
    (uint32_t)(15485907386658061715ULL ^ ( 8ULL * 11400714819323198485ULL)),
    (uint32_t)(15485907386658061715ULL ^ ( 9ULL * 11400714819323198485ULL)),
    (uint32_t)(15485907386658061715ULL ^ (10ULL * 11400714819323198485ULL)),
    (uint32_t)(15485907386658061715ULL ^ (11ULL * 11400714819323198485ULL)),
    (uint32_t)(15485907386658061715ULL ^ (12ULL * 11400714819323198485ULL)),
    (uint32_t)(15485907386658061715ULL ^ (13ULL * 11400714819323198485ULL)),
    (uint32_t)(15485907386658061715ULL ^ (14ULL * 11400714819323198485ULL)),
    (uint32_t)(15485907386658061715ULL ^ (15ULL * 11400714819323198485ULL)),
};

// One thread = one (level, pixel). Blocks are assigned so that all blocks of a
// given level land on ONE XCD (blockIdx % 8 round-robin): XCD k gets levels
// {k, 15-k}, whose combined touched-table footprint fits the 4 MiB per-XCD L2.
__global__ __launch_bounds__(256)
void HashTableEncoder2D_59339268161685_kernel(const float* __restrict__ tables,
                                              const int* __restrict__ x0,
                                              const int* __restrict__ y0,
                                              float* __restrict__ out)
{
    const int k = blockIdx.x & 7;          // XCD id (dispatch round-robin)
    const int w = blockIdx.x >> 3;         // sequence within this XCD [0, 8192)
    const int l = (w < BLOCKS_PER_LEVEL) ? k : (15 - k);

    const int p = ((w & (BLOCKS_PER_LEVEL - 1)) << 8) | threadIdx.x; // pixel [0, 1M)
    const int j = p & (CROP - 1);
    const int i = (p >> 8) & (CROP - 1);
    const int b = p >> 16;

    // pixel-center global coordinates; exact in f32
    const float px = (float)x0[b] + ((float)j + 0.5f);
    const float py = (float)y0[b] + ((float)i + 0.5f);

    const float scale = (float)c_levelN[l] * (1.0f / 4096.0f);
    const uint32_t seed = c_seed[l];

    const float gx = px * scale;
    const float gy = py * scale;
    const float fx0f = floorf(gx);
    const float fy0f = floorf(gy);
    const int ix0 = (int)fx0f;
    const int iy0 = (int)fy0f;
    const float fx = gx - fx0f;
    const float fy = gy - fy0f;

    const uint32_t hx0 = (uint32_t)ix0 * 2654435761u;
    const uint32_t hx1 = (uint32_t)(ix0 + 1) * 2654435761u;
    const uint32_t hy0 = ((uint32_t)iy0 * 805459861u) ^ seed;
    const uint32_t hy1 = ((uint32_t)(iy0 + 1) * 805459861u) ^ seed;

    const float2* __restrict__ T =
        (const float2*)(tables + (size_t)l * (size_t)(TABLE_SIZE * 2));
    const float2 f00 = T[(hx0 ^ hy0) & (TABLE_SIZE - 1)];
    const float2 f10 = T[(hx1 ^ hy0) & (TABLE_SIZE - 1)];
    const float2 f01 = T[(hx0 ^ hy1) & (TABLE_SIZE - 1)];
    const float2 f11 = T[(hx1 ^ hy1) & (TABLE_SIZE - 1)];

    const float w00 = (1.0f - fx) * (1.0f - fy);
    const float w10 = fx * (1.0f - fy);
    const float w01 = (1.0f - fx) * fy;
    const float w11 = fx * fy;

    const float e0 = w00 * f00.x + w10 * f10.x + w01 * f01.x + w11 * f11.x;
    const float e1 = w00 * f00.y + w10 * f10.y + w01 * f01.y + w11 * f11.y;

    // nontemporal: keep the 134 MB output stream from evicting table lines in L2
    float* outp = out + (size_t)b * (size_t)(32 * CROP * CROP) + i * CROP + j;
    __builtin_nontemporal_store(e0, outp + (2 * l)     * (CROP * CROP));
    __builtin_nontemporal_store(e1, outp + (2 * l + 1) * (CROP * CROP));
}

extern "C" void kernel_launch(void* const* d_in, const int* in_sizes, int n_in,
                              void* d_out, int out_size, void* d_ws, size_t ws_size,
                              hipStream_t stream)
{
    const float* tables = (const float*)d_in[0];
    const int*   x0     = (const int*)d_in[1];
    const int*   y0     = (const int*)d_in[2];
    float* out = (float*)d_out;

    const int blocks = LEVELS * BLOCKS_PER_LEVEL;   // 65536 blocks x 256 thr
    HashTableEncoder2D_59339268161685_kernel<<<blocks, 256, 0, stream>>>(tables, x0, y0, out);
}

// Round 3
// 60.074 us; speedup vs baseline: 2.7096x; 2.5832x over previous
//
#include <hip/hip_runtime.h>
#include <cstdint>
#include <cstddef>

#define LEVELS 16
#define TABLE_SIZE 524288   // 2^19
#define CROP 256            // memorized_crop_size
#define TILE 32             // pixel tile per block (32x32)
#define NXMAX 57            // max corners per axis: floor(31*1.7104)+2 = 55 (+margin)

// grid resolutions: int(round(16 * 1.5^l)), Python banker's rounding (121.5 -> 122)
__device__ __constant__ int c_levelN[LEVELS] = {
    16, 24, 36, 54, 81, 122, 182, 273, 410, 615, 923, 1384, 2076, 3114, 4671, 7006
};
// seeds: (15485907386658061715 ^ (l * 11400714819323198485)) & 0xFFFFFFFF
__device__ __constant__ uint32_t c_seed[LEVELS] = {
    (uint32_t)(15485907386658061715ULL ^ ( 0ULL * 11400714819323198485ULL)),
    (uint32_t)(15485907386658061715ULL ^ ( 1ULL * 11400714819323198485ULL)),
    (uint32_t)(15485907386658061715ULL ^ ( 2ULL * 11400714819323198485ULL)),
    (uint32_t)(15485907386658061715ULL ^ ( 3ULL * 11400714819323198485ULL)),
    (uint32_t)(15485907386658061715ULL ^ ( 4ULL * 11400714819323198485ULL)),
    (uint32_t)(15485907386658061715ULL ^ ( 5ULL * 11400714819323198485ULL)),
    (uint32_t)(15485907386658061715ULL ^ ( 6ULL * 11400714819323198485ULL)),
    (uint32_t)(15485907386658061715ULL ^ ( 7ULL * 11400714819323198485ULL)),
    (uint32_t)(15485907386658061715ULL ^ ( 8ULL * 11400714819323198485ULL)),
    (uint32_t)(15485907386658061715ULL ^ ( 9ULL * 11400714819323198485ULL)),
    (uint32_t)(15485907386658061715ULL ^ (10ULL * 11400714819323198485ULL)),
    (uint32_t)(15485907386658061715ULL ^ (11ULL * 11400714819323198485ULL)),
    (uint32_t)(15485907386658061715ULL ^ (12ULL * 11400714819323198485ULL)),
    (uint32_t)(15485907386658061715ULL ^ (13ULL * 11400714819323198485ULL)),
    (uint32_t)(15485907386658061715ULL ^ (14ULL * 11400714819323198485ULL)),
    (uint32_t)(15485907386658061715ULL ^ (15ULL * 11400714819323198485ULL)),
};

// Tile-staged encoder: per (block, level), the distinct grid corners the tile
// touches are gathered ONCE into LDS (dedup ~11x vs per-pixel taps — attacks
// the per-lane gather-address bottleneck), then pixels bilinear out of LDS.
__global__ __launch_bounds__(256)
void HashTableEncoder2D_59339268161685_kernel(const float* __restrict__ tables,
                                              const int* __restrict__ x0,
                                              const int* __restrict__ y0,
                                              float* __restrict__ out)
{
    __shared__ float2 lds[NXMAX * NXMAX];   // 57*57*8 = 25,992 B

    // blockIdx = xcd + 8*s  (dispatch round-robins XCDs): XCD k gets crops {2k, 2k+1}
    const int xcd  = blockIdx.x & 7;
    const int s    = blockIdx.x >> 3;        // [0,128)
    const int b    = 2 * xcd + (s >> 6);     // crop id
    const int tile = s & 63;                 // 8x8 tiles of 32x32 px
    const int tx = (tile & 7) * TILE;
    const int ty = (tile >> 3) * TILE;

    const int tid = threadIdx.x;

    // global pixel-center coords of tile origin; exact in f32 (n+0.5, n<2^22)
    const float bx = (float)(x0[b] + tx) + 0.5f;
    const float by = (float)(y0[b] + ty) + 0.5f;

    float* outb = out + (size_t)b * (size_t)(32 * CROP * CROP);

    for (int l = 0; l < LEVELS; ++l) {
        const float scale = (float)c_levelN[l] * (1.0f / 4096.0f); // exact dyadic
        const uint32_t seed = c_seed[l];

        // corner range this tile needs (f32 mul is monotone -> covers all pixels)
        const int ixlo = (int)floorf(bx * scale);
        const int iylo = (int)floorf(by * scale);
        const int nx = ((int)floorf((bx + 31.0f) * scale) + 1) - ixlo + 1; // <= 56
        const int ny = ((int)floorf((by + 31.0f) * scale) + 1) - iylo + 1;

        __syncthreads();   // previous level's LDS readers done

        // stage nx*ny corners (row stride NXMAX); lds[row*57+col] = T[hash(ix,iy)]
        const float2* __restrict__ T =
            (const float2*)(tables + (size_t)l * (size_t)(TABLE_SIZE * 2));
        for (int c = tid; c < NXMAX * ny; c += 256) {
            const int row = c / NXMAX;            // const-div -> magic mul
            const int col = c - row * NXMAX;
            if (col < nx) {
                const uint32_t h = ((uint32_t)(ixlo + col) * 2654435761u)
                                 ^ ((uint32_t)(iylo + row) * 805459861u) ^ seed;
                lds[c] = T[h & (TABLE_SIZE - 1)];
            }
        }
        __syncthreads();

        // 4 pixels per thread, bilinear from LDS
        #pragma unroll
        for (int k = 0; k < 4; ++k) {
            const int p = tid + k * 256;          // [0,1024)
            const int j = p & (TILE - 1);
            const int i = p >> 5;
            const float gx = (bx + (float)j) * scale;  // bx+j exact == ref px
            const float gy = (by + (float)i) * scale;
            const float fxf = floorf(gx);
            const float fyf = floorf(gy);
            const float fx = gx - fxf;
            const float fy = gy - fyf;
            const int base = ((int)fyf - iylo) * NXMAX + ((int)fxf - ixlo);

            const float2 f00 = lds[base];
            const float2 f10 = lds[base + 1];
            const float2 f01 = lds[base + NXMAX];
            const float2 f11 = lds[base + NXMAX + 1];

            const float w00 = (1.0f - fx) * (1.0f - fy);
            const float w10 = fx * (1.0f - fy);
            const float w01 = (1.0f - fx) * fy;
            const float w11 = fx * fy;

            const float e0 = w00 * f00.x + w10 * f10.x + w01 * f01.x + w11 * f11.x;
            const float e1 = w00 * f00.y + w10 * f10.y + w01 * f01.y + w11 * f11.y;

            float* o = outb + (size_t)(2 * l) * (CROP * CROP)
                            + (ty + i) * CROP + (tx + j);
            __builtin_nontemporal_store(e0, o);
            __builtin_nontemporal_store(e1, o + CROP * CROP);
        }
    }
}

extern "C" void kernel_launch(void* const* d_in, const int* in_sizes, int n_in,
                              void* d_out, int out_size, void* d_ws, size_t ws_size,
                              hipStream_t stream)
{
    const float* tables = (const float*)d_in[0];
    const int*   x0     = (const int*)d_in[1];
    const int*   y0     = (const int*)d_in[2];
    float* out = (float*)d_out;

    // 16 crops x 64 tiles = 1024 blocks x 256 threads
    HashTableEncoder2D_59339268161685_kernel<<<1024, 256, 0, stream>>>(tables, x0, y0, out);
}